// Round 14
// baseline (957.484 us; speedup 1.0000x reference)
//
#include <hip/hip_runtime.h>

#define N_TOK 8192
#define DIM   2048
#define FFN   1408

// ---------- ws layout (bytes); top = 258,932,992 ----------
// xb  [0, 33.5M)        prep(router) w -> gather r
// hp  [0, 49.0M)        gemm_gu w -> gemm_down r   (aliases dead xb)
// xgp [49.0M, 120.3M)   gather w -> gemm_gu r
// eo  [49.0M, 116.1M)   bf16, gemm_down w -> combine r (aliases dead xgp)
// p1  [120.3M, 212.6M)  prep(pack_gu) w -> gemm_gu r
// p2  [212.6M, 258.7M)  prep(pack_d) w -> gemm_down r
#define XB_OFF  0ull
#define HP_OFF  0ull
#define XGP_OFF 49020928ull
#define EO_OFF  49020928ull
#define P1_OFF  120324096ull
#define P2_OFF  212598784ull
#define LPK_OFF 258736128ull
#define TI_OFF  258801664ull
#define TW_OFF  258834432ull
#define TP_OFF  258867200ull
#define ST_OFF  258932736ull

typedef __bf16 bf16x8 __attribute__((ext_vector_type(8)));
typedef float  f32x4  __attribute__((ext_vector_type(4)));
typedef int    int4v  __attribute__((ext_vector_type(4)));
typedef __attribute__((address_space(1))) void as1_void;
typedef __attribute__((address_space(3))) void as3_void;

__device__ __forceinline__ void gload16(const void* g, void* l) {
  __builtin_amdgcn_global_load_lds((as1_void*)g, (as3_void*)l, 16, 0, 0);
}

__device__ __forceinline__ ushort f2bf(float f) {
  unsigned u = __builtin_bit_cast(unsigned, f);
  u += 0x7FFFu + ((u >> 16) & 1u);
  return (ushort)(u >> 16);
}
__device__ __forceinline__ float blo(unsigned w) { return __builtin_bit_cast(float, w << 16); }
__device__ __forceinline__ float bhi(unsigned w) { return __builtin_bit_cast(float, w & 0xffff0000u); }

__device__ __forceinline__ int4v dsread(int addr) {
  int4v d;
  asm volatile("ds_read_b128 %0, %1" : "=v"(d) : "v"(addr));
  return d;
}

#define BAR()   __builtin_amdgcn_s_barrier()
#define MFMA16(a, b, c) __builtin_amdgcn_mfma_f32_16x16x32_bf16(a, b, c, 0, 0, 0)
#define BC(x) __builtin_bit_cast(bf16x8, x)

// 8KB unit = 128 rows x 32 k bf16. Piece (row, s): q=row>>1,
// p = (((row&1)<<2)|s) ^ (q&7); byte = q*128 + p*16.
__device__ __forceinline__ int swz(int row, int s) {
  int q = row >> 1;
  int p = (((row & 1) << 2) | s) ^ (q & 7);
  return q * 128 + p * 16;
}

// =====================================================================
// prep: fused router (+x->bf16) | pack_gu | pack_d.  All independent.
// blocks [0,512) router ; [512, 11776) pack_gu ; [11776, 17408) pack_d.
// =====================================================================
__global__ __launch_bounds__(256) void prep_kernel(
    const float* __restrict__ x, const float* __restrict__ rw,
    ushort* __restrict__ xb, int* __restrict__ topi, float* __restrict__ topw,
    int* __restrict__ cnt, unsigned long long* __restrict__ psum,
    const float* __restrict__ wg, const float* __restrict__ wu,
    const float* __restrict__ wd, char* __restrict__ p1, char* __restrict__ p2)
{
  __shared__ char smem[16640];
  int b = blockIdx.x;

  if (b < 512) {
    // ---------------- router ----------------
    int tid = threadIdx.x, lane = tid & 63, wv = tid >> 6;
    float (*sP)[8] = (float(*)[8])smem;
    int   (*sC)[8] = (int(*)[8])(smem + 128);
    float pacc[8]; int cacc[8];
    #pragma unroll
    for (int e = 0; e < 8; ++e) { pacc[e] = 0.f; cacc[e] = 0; }

    #pragma unroll 1
    for (int it = 0; it < 4; ++it) {
      int t = b * 16 + wv * 4 + it;
      const float4* xr = (const float4*)(x + (size_t)t * DIM);
      float acc[8];
      #pragma unroll
      for (int e = 0; e < 8; ++e) acc[e] = 0.f;
      #pragma unroll 1
      for (int i = 0; i < 8; ++i) {
        int j = i * 64 + lane;
        float4 v = xr[j];
        ushort4 o; o.x = f2bf(v.x); o.y = f2bf(v.y); o.z = f2bf(v.z); o.w = f2bf(v.w);
        *(ushort4*)(xb + (size_t)t * DIM + (size_t)j * 4) = o;
        const float* rr = rw + (size_t)j * 32;
        #pragma unroll
        for (int c = 0; c < 4; ++c) {
          float xv = (&v.x)[c];
          const float4* r4 = (const float4*)(rr + c * 8);
          float4 q0 = r4[0], q1 = r4[1];
          acc[0] += xv * q0.x; acc[1] += xv * q0.y; acc[2] += xv * q0.z; acc[3] += xv * q0.w;
          acc[4] += xv * q1.x; acc[5] += xv * q1.y; acc[6] += xv * q1.z; acc[7] += xv * q1.w;
        }
      }
      #pragma unroll
      for (int off = 32; off; off >>= 1) {
        #pragma unroll
        for (int e = 0; e < 8; ++e) acc[e] += __shfl_xor(acc[e], off);
      }
      float m = acc[0];
      #pragma unroll
      for (int e = 1; e < 8; ++e) m = fmaxf(m, acc[e]);
      float p[8], s = 0.f;
      #pragma unroll
      for (int e = 0; e < 8; ++e) { p[e] = __expf(acc[e] - m); s += p[e]; }
      float inv = 1.f / s;
      int i1 = 0; float p1v = p[0];
      #pragma unroll
      for (int e = 1; e < 8; ++e) if (p[e] > p1v) { p1v = p[e]; i1 = e; }
      int i2 = -1; float p2v = -1.f;
      #pragma unroll
      for (int e = 0; e < 8; ++e) if (e != i1 && p[e] > p2v) { p2v = p[e]; i2 = e; }
      float w1 = p1v / (p1v + p2v);
      if (lane == 0) {
        topi[t] = i1 | (i2 << 8);
        topw[t] = w1;
        #pragma unroll
        for (int e = 0; e < 8; ++e) pacc[e] += p[e] * inv;
        cacc[i1]++; cacc[i2]++;
      }
    }
    if (lane == 0) {
      #pragma unroll
      for (int e = 0; e < 8; ++e) { sP[wv][e] = pacc[e]; sC[wv][e] = cacc[e]; }
    }
    __syncthreads();
    if (tid < 8) {
      float ps = sP[0][tid] + sP[1][tid] + sP[2][tid] + sP[3][tid];
      int   cs = sC[0][tid] + sC[1][tid] + sC[2][tid] + sC[3][tid];
      atomicAdd(&cnt[tid], cs);
      atomicAdd(&psum[tid], (unsigned long long)((double)ps * 1099511627776.0));
    }
  } else if (b < 11776) {
    // ---------------- pack_gu: rows 0-63 gate, 64-127 up ----------------
    int q_ = b - 512;
    int j = q_ & 63, rest = q_ >> 6;
    int tn = rest % 22, e = rest / 22;
    float (*tg)[65] = (float(*)[65])smem;
    float (*tu)[65] = (float(*)[65])(smem + 8320);
    int t = threadIdx.x;
    const float* gs = wg + ((size_t)e * DIM + j * 32) * FFN + tn * 64;
    const float* us = wu + ((size_t)e * DIM + j * 32) * FFN + tn * 64;
    #pragma unroll
    for (int k2 = 0; k2 < 2; ++k2) {
      int idx = t + k2 * 256;
      int kk = idx >> 4, fq = idx & 15;
      *(float4*)&tg[kk][fq * 4] = *(const float4*)(gs + (size_t)kk * FFN + fq * 4);
      *(float4*)&tu[kk][fq * 4] = *(const float4*)(us + (size_t)kk * FFN + fq * 4);
    }
    __syncthreads();
    char* dst = p1 + ((size_t)((e * 22 + tn) * 64 + j)) * 8192;
    #pragma unroll
    for (int k2 = 0; k2 < 2; ++k2) {
      int L = t + k2 * 256;
      int q = L >> 3, v = (L & 7) ^ (q & 7);
      int r = 2 * q + (v >> 2), s = v & 3;
      const float* col = (r < 64) ? &tg[s * 8][r] : &tu[s * 8][r - 64];
      ushort u8[8];
      #pragma unroll
      for (int i = 0; i < 8; ++i) u8[i] = f2bf(col[i * 65]);
      *(ushort4*)(dst + (size_t)L * 16) = *(ushort4*)&u8[0];
      *(ushort4*)(dst + (size_t)L * 16 + 8) = *(ushort4*)&u8[4];
    }
  } else {
    // ---------------- pack_d: rows = 128 d-cols ----------------
    int q_ = b - 11776;
    int j = q_ % 44, rest = q_ / 44;
    int tn = rest & 15, e = rest >> 4;
    float (*t2)[129] = (float(*)[129])smem;
    int t = threadIdx.x;
    const float* src = wd + ((size_t)e * FFN + j * 32) * DIM + tn * 128;
    #pragma unroll
    for (int k2 = 0; k2 < 4; ++k2) {
      int idx = t + k2 * 256;
      int kk = idx >> 5, dq = idx & 31;
      *(float4*)&t2[kk][dq * 4] = *(const float4*)(src + (size_t)kk * DIM + dq * 4);
    }
    __syncthreads();
    char* dst = p2 + ((size_t)((e * 16 + tn) * 44 + j)) * 8192;
    #pragma unroll
    for (int k2 = 0; k2 < 2; ++k2) {
      int L = t + k2 * 256;
      int q = L >> 3, v = (L & 7) ^ (q & 7);
      int r = 2 * q + (v >> 2), s = v & 3;
      ushort u8[8];
      #pragma unroll
      for (int i = 0; i < 8; ++i) u8[i] = f2bf(t2[s * 8 + i][r]);
      *(ushort4*)(dst + (size_t)L * 16) = *(ushort4*)&u8[0];
      *(ushort4*)(dst + (size_t)L * 16 + 8) = *(ushort4*)&u8[4];
    }
  }
}

// ---------------- placement (scan fused: prefix computed locally) ----------------
__global__ __launch_bounds__(256) void place_kernel(
    const int* __restrict__ topi, int* __restrict__ stats,
    const unsigned long long* __restrict__ psum,
    int* __restrict__ lpk, int2* __restrict__ tpos, float* __restrict__ aux_out)
{
  int cnt[8], pre[8];
  int acc = 0;
  #pragma unroll
  for (int e = 0; e < 8; ++e) { cnt[e] = stats[e]; pre[e] = acc; acc += cnt[e]; }

  if (blockIdx.x == 0 && threadIdx.x == 0) {
    int tb = 0;
    for (int e = 0; e < 8; ++e) {
      stats[16 + e] = pre[e];
      stats[24 + e] = tb;
      tb += (cnt[e] + 127) >> 7;
    }
    stats[32] = tb;
    double s = 0.0;
    for (int e = 0; e < 8; ++e)
      s += (double)cnt[e] * ((double)psum[e] * (1.0 / 1099511627776.0));
    aux_out[0] = (float)(4.0 * s / ((double)N_TOK * (double)N_TOK));
  }

  int t = blockIdx.x * 256 + threadIdx.x;
  if (t >= N_TOK) return;
  int pk = topi[t];
  int e1 = pk & 0xff, e2 = (pk >> 8) & 0xff;
  int p1 = pre[e1] + atomicAdd(&stats[8 + e1], 1);
  lpk[p1] = t;
  int p2 = pre[e2] + atomicAdd(&stats[8 + e2], 1);
  lpk[p2] = t;
  tpos[t] = make_int2(p1, p2);
}

// ---------------- gather bf16 tokens into chunk-image layout (x4 split) ----------------
__global__ __launch_bounds__(256) void gather_x_kernel(
    const ushort* __restrict__ xb, const int* __restrict__ lpk,
    const int* __restrict__ stats, char* __restrict__ xgp)
{
  int b = blockIdx.x;
  int tile = b >> 2;
  if (tile >= stats[32]) return;
  int e = 0;
  #pragma unroll
  for (int k = 1; k < 8; ++k) if (tile >= stats[24 + k]) e = k;
  int tloc = tile - stats[24 + e];
  int abase = stats[16 + e], Me = stats[e];
  int quad = b & 3;
  int lane = threadIdx.x & 63, wv = threadIdx.x >> 6;
  char* base = xgp + (size_t)tile * 64 * 8192;
  #pragma unroll 1
  for (int r = quad * 32 + wv; r < quad * 32 + 32; r += 4) {
    int lrow = tloc * 128 + r;
    bool valid = lrow < Me;
    const char* src = (const char*)xb + (valid ? (size_t)lpk[abase + lrow] * (DIM * 2) : 0);
    int q = r >> 1;
    #pragma unroll
    for (int it = 0; it < 4; ++it) {
      int c16 = it * 64 + lane;
      int j = c16 >> 2, s = c16 & 3;
      uint4 v;
      if (valid) v = *(const uint4*)(src + c16 * 16);
      else       v = make_uint4(0, 0, 0, 0);
      int p = (((r & 1) << 2) | s) ^ (q & 7);
      *(uint4*)(base + (size_t)j * 8192 + q * 128 + p * 16) = v;
    }
  }
}

// =====================================================================
// GEMM core: 256x128 tile, 2 waves (128 threads), wave = one 128-row
// A-image x all 128 B-rows (128x128 per wave -> 64 FLOP/LDS-byte, 1.5x
// round-13; LDS-read demand/CU drops to ~770 cyc < MFMA 1240 cyc).
// acc[8][8] f32x4 (~256 VGPR) -> 1 wave/SIMD; 2 blocks/CU via 72KB LDS.
// 3-slot ring, depth-2 prefetch, vmcnt(24/12/0); lgkm split 4/0.
// XCD-locality: bid&7 -> XCD -> expert; within XCD: tm outer, tn fast.
// =====================================================================

#define GSTAGE(J, BUF) do { \
  size_t go_ = (size_t)(J) * 8192 + lane * 16; \
  const char* aw_ = wv ? aP1 : aP0; \
  char* db_ = sm + (BUF) * 24576 + wv * 8192; \
  _Pragma("unroll") for (int i_ = 0; i_ < 8; ++i_) \
    gload16(aw_ + go_ + i_ * 1024, db_ + i_ * 1024); \
  char* dbB_ = sm + (BUF) * 24576 + 16384 + wv * 4096; \
  _Pragma("unroll") for (int i_ = 0; i_ < 4; ++i_) \
    gload16(bP + go_ + wv * 4096 + i_ * 1024, dbB_ + i_ * 1024); \
} while (0)

#define KLOOP(NCH) \
  GSTAGE(0, 0); \
  GSTAGE(1, 1); \
  { int cur = 0, st = 2; \
  _Pragma("unroll 1") \
  for (int j = 0; j < (NCH); ++j) { \
    if (j + 2 < (NCH)) { \
      GSTAGE(j + 2, st); \
      asm volatile("s_waitcnt vmcnt(24)" ::: "memory"); \
    } else if (j + 2 == (NCH)) { \
      asm volatile("s_waitcnt vmcnt(12)" ::: "memory"); \
    } else { \
      asm volatile("s_waitcnt vmcnt(0)" ::: "memory"); \
    } \
    BAR(); \
    int sb = cur * 24576; \
    int4v va[8], vb[8]; \
    _Pragma("unroll") for (int n = 0; n < 4; ++n) vb[n] = dsread(sb + adB[n]); \
    _Pragma("unroll") for (int m = 0; m < 8; ++m) va[m] = dsread(sb + adA[m]); \
    _Pragma("unroll") for (int n = 4; n < 8; ++n) vb[n] = dsread(sb + adB[n]); \
    asm volatile("s_waitcnt lgkmcnt(4)" ::: "memory"); \
    __builtin_amdgcn_sched_barrier(0); \
    __builtin_amdgcn_s_setprio(1); \
    _Pragma("unroll") for (int m = 0; m < 8; ++m) \
      _Pragma("unroll") for (int n = 0; n < 4; ++n) \
        acc[m][n] = MFMA16(BC(va[m]), BC(vb[n]), acc[m][n]); \
    __builtin_amdgcn_s_setprio(0); \
    asm volatile("s_waitcnt lgkmcnt(0)" ::: "memory"); \
    __builtin_amdgcn_sched_barrier(0); \
    __builtin_amdgcn_s_setprio(1); \
    _Pragma("unroll") for (int m = 0; m < 8; ++m) \
      _Pragma("unroll") for (int n = 4; n < 8; ++n) \
        acc[m][n] = MFMA16(BC(va[m]), BC(vb[n]), acc[m][n]); \
    __builtin_amdgcn_s_setprio(0); \
    BAR(); \
    cur = (cur == 2) ? 0 : cur + 1; \
    st  = (st  == 2) ? 0 : st  + 1; \
  } }

// GEMM1: A = 256 tokens (2 images, one per wave), B = {gate,up} image.
// Wave owns 128 tokens x 128 B-rows -> SiLU in-register (gate n, up n+4).
__global__ __launch_bounds__(128, 1) void gemm_gu_kernel(
    const char* __restrict__ xgp, const char* __restrict__ p1,
    const int* __restrict__ stats, char* __restrict__ hp)
{
  int bid = blockIdx.x;
  int e = bid & 7;
  int Ll = bid >> 3;
  int tm = Ll / 22, tn = Ll % 22;
  int Me = stats[e];
  if (tm * 256 >= Me) return;
  int tb = stats[24 + e];

  __shared__ char sm[73728];
  int tid = threadIdx.x, lane = tid & 63, wv = tid >> 6;
  const char* aP0 = xgp + (size_t)(tb + tm * 2) * 64 * 8192;
  const char* aP1 = aP0 + 64 * 8192;
  const char* bP = p1 + (size_t)((e * 22 + tn) * 64) * 8192;

  int s = lane >> 4;
  int adA[8], adB[8];
  #pragma unroll
  for (int m = 0; m < 8; ++m) adA[m] = wv * 8192 + swz(m * 16 + (lane & 15), s);
  #pragma unroll
  for (int n = 0; n < 8; ++n) adB[n] = 16384 + swz(n * 16 + (lane & 15), s);

  f32x4 acc[8][8];
  #pragma unroll
  for (int m = 0; m < 8; ++m)
    #pragma unroll
    for (int n = 0; n < 8; ++n) acc[m][n] = (f32x4){0, 0, 0, 0};

  KLOOP(64);

  // epilogue: gate = acc[m][n], up = acc[m][n+4] -> in-register SiLU.
  int r0 = (lane >> 4) * 4, cl = lane & 15;
  char* hb = hp + (size_t)(tb + tm * 2 + wv) * 44 * 8192;
  #pragma unroll
  for (int m = 0; m < 8; ++m) {
    #pragma unroll
    for (int r = 0; r < 4; ++r) {
      int lr = m * 16 + r0 + r;
      if (tm * 256 + wv * 128 + lr < Me) {
        int q = lr >> 1;
        #pragma unroll
        for (int n = 0; n < 4; ++n) {
          float g = acc[m][n][r];
          float u = acc[m][n + 4][r];
          float hv = g * u / (1.f + __expf(-g));
          int f = tn * 64 + n * 16 + cl;
          int j2 = f >> 5, s2 = (f >> 3) & 3, i2 = f & 7;
          int p = (((lr & 1) << 2) | s2) ^ (q & 7);
          *(ushort*)(hb + (size_t)j2 * 8192 + q * 128 + p * 16 + i2 * 2) = f2bf(hv);
        }
      }
    }
  }
}

// GEMM2: A = h (2 images, one per wave), B = down image (128 d-cols).
__global__ __launch_bounds__(128, 1) void gemm_down_kernel(
    const char* __restrict__ hp, const char* __restrict__ p2,
    const int* __restrict__ stats, ushort* __restrict__ eo)
{
  int bid = blockIdx.x;
  int e = bid & 7;
  int Ll = bid >> 3;
  int tm = Ll >> 4, tn = Ll & 15;
  int Me = stats[e];
  if (tm * 256 >= Me) return;
  int tb = stats[24 + e], abase = stats[16 + e];

  __shared__ char sm[73728];
  int tid = threadIdx.x, lane = tid & 63, wv = tid >> 6;
  const char* aP0 = hp + (size_t)(tb + tm * 2) * 44 * 8192;
  const char* aP1 = aP0 + 44 * 8192;
  const char* bP = p2 + (size_t)((e * 16 + tn) * 44) * 8192;

  int s = lane >> 4;
  int adA[8], adB[8];
  #pragma unroll
  for (int m = 0; m < 8; ++m) adA[m] = wv * 8192 + swz(m * 16 + (lane & 15), s);
  #pragma unroll
  for (int n = 0; n < 8; ++n) adB[n] = 16384 + swz(n * 16 + (lane & 15), s);

  f32x4 acc[8][8];
  #pragma unroll
  for (int m = 0; m < 8; ++m)
    #pragma unroll
    for (int n = 0; n < 8; ++n) acc[m][n] = (f32x4){0, 0, 0, 0};

  KLOOP(44);

  int c0 = lane & 15, r0 = (lane >> 4) * 4;
  #pragma unroll
  for (int m = 0; m < 8; ++m) {
    #pragma unroll
    for (int r = 0; r < 4; ++r) {
      int lrow = tm * 256 + wv * 128 + m * 16 + r0 + r;
      if (lrow < Me) {
        ushort* dst = eo + (size_t)(abase + lrow) * DIM + tn * 128 + c0;
        #pragma unroll
        for (int n = 0; n < 8; ++n) dst[n * 16] = f2bf(acc[m][n][r]);
      }
    }
  }
}

// ---------------- combine: out[t] = w1*eo[p1] + w2*eo[p2] (bf16 partials) ----------------
__global__ __launch_bounds__(256) void combine_kernel(
    const ushort* __restrict__ eo, const int2* __restrict__ tpos,
    const float* __restrict__ topw, float* __restrict__ out)
{
  int t = blockIdx.x;
  int2 tp = tpos[t];
  float w1 = topw[t], w2 = 1.f - w1;
  const uint4* r1 = (const uint4*)(eo + (size_t)tp.x * DIM);
  const uint4* r2 = (const uint4*)(eo + (size_t)tp.y * DIM);
  float4* o = (float4*)(out + (size_t)t * DIM);
  int i = threadIdx.x;
  uint4 a = r1[i], b = r2[i];
  float4 c0, c1;
  c0.x = w1 * blo(a.x) + w2 * blo(b.x);  c0.y = w1 * bhi(a.x) + w2 * bhi(b.x);
  c0.z = w1 * blo(a.y) + w2 * blo(b.y);  c0.w = w1 * bhi(a.y) + w2 * bhi(b.y);
  c1.x = w1 * blo(a.z) + w2 * blo(b.z);  c1.y = w1 * bhi(a.z) + w2 * bhi(b.z);
  c1.z = w1 * blo(a.w) + w2 * blo(b.w);  c1.w = w1 * bhi(a.w) + w2 * bhi(b.w);
  o[i * 2] = c0;
  o[i * 2 + 1] = c1;
}

extern "C" void kernel_launch(void* const* d_in, const int* in_sizes, int n_in,
                              void* d_out, int out_size, void* d_ws, size_t ws_size,
                              hipStream_t stream)
{
  const float* x  = (const float*)d_in[0];
  const float* rw = (const float*)d_in[1];
  const float* wg = (const float*)d_in[2];
  const float* wu = (const float*)d_in[3];
  const float* wd = (const float*)d_in[4];
  float* out = (float*)d_out;

  char* ws = (char*)d_ws;
  ushort* xb   = (ushort*)(ws + XB_OFF);
  char*   hp   = ws + HP_OFF;
  char*   xgp  = ws + XGP_OFF;
  ushort* eo   = (ushort*)(ws + EO_OFF);
  char*   p1   = ws + P1_OFF;
  char*   p2   = ws + P2_OFF;
  int*    lpk  = (int*)(ws + LPK_OFF);
  int*    topi = (int*)(ws + TI_OFF);
  float*  topw = (float*)(ws + TW_OFF);
  int2*   tpos = (int2*)(ws + TP_OFF);
  int*    stats = (int*)(ws + ST_OFF);
  unsigned long long* psum = (unsigned long long*)(ws + ST_OFF + 192);

  hipMemsetAsync(ws + ST_OFF, 0, 256, stream);

  prep_kernel<<<17408, 256, 0, stream>>>(x, rw, xb, topi, topw, stats, psum,
                                         wg, wu, wd, p1, p2);
  place_kernel<<<32, 256, 0, stream>>>(topi, stats, psum, lpk, tpos,
                                       out + (size_t)out_size - 1);

  gather_x_kernel<<<544, 256, 0, stream>>>(xb, lpk, stats, xgp);

  gemm_gu_kernel<<<2816, 128, 0, stream>>>(xgp, p1, stats, hp);
  gemm_down_kernel<<<2048, 128, 0, stream>>>(hp, p2, stats, eo);

  combine_kernel<<<8192, 256, 0, stream>>>(eo, tpos, topw, out);
}

// Round 15
// 517.617 us; speedup vs baseline: 1.8498x; 1.8498x over previous
//
#include <hip/hip_runtime.h>

#define N_TOK 8192
#define DIM   2048
#define FFN   1408

// ---------- ws layout (bytes); top = 258,932,992 ----------
// xb  [0, 33.5M)        prep(router) w -> gather r
// hp  [0, 49.0M)        gemm_gu w -> gemm_down r   (aliases dead xb)
// xgp [49.0M, 120.3M)   gather w -> gemm_gu r
// eo  [49.0M, 116.1M)   bf16, gemm_down w -> combine r (aliases dead xgp)
// p1  [120.3M, 212.6M)  prep(pack_gu) w -> gemm_gu r
// p2  [212.6M, 258.7M)  prep(pack_d) w -> gemm_down r
#define XB_OFF  0ull
#define HP_OFF  0ull
#define XGP_OFF 49020928ull
#define EO_OFF  49020928ull
#define P1_OFF  120324096ull
#define P2_OFF  212598784ull
#define LPK_OFF 258736128ull
#define TI_OFF  258801664ull
#define TW_OFF  258834432ull
#define TP_OFF  258867200ull
#define ST_OFF  258932736ull

typedef __bf16 bf16x8 __attribute__((ext_vector_type(8)));
typedef float  f32x4  __attribute__((ext_vector_type(4)));
typedef int    int4v  __attribute__((ext_vector_type(4)));
typedef __attribute__((address_space(1))) void as1_void;
typedef __attribute__((address_space(3))) void as3_void;

__device__ __forceinline__ void gload16(const void* g, void* l) {
  __builtin_amdgcn_global_load_lds((as1_void*)g, (as3_void*)l, 16, 0, 0);
}

__device__ __forceinline__ ushort f2bf(float f) {
  unsigned u = __builtin_bit_cast(unsigned, f);
  u += 0x7FFFu + ((u >> 16) & 1u);
  return (ushort)(u >> 16);
}
__device__ __forceinline__ float blo(unsigned w) { return __builtin_bit_cast(float, w << 16); }
__device__ __forceinline__ float bhi(unsigned w) { return __builtin_bit_cast(float, w & 0xffff0000u); }

__device__ __forceinline__ int4v dsread(int addr) {
  int4v d;
  asm volatile("ds_read_b128 %0, %1" : "=v"(d) : "v"(addr));
  return d;
}

#define BAR()   __builtin_amdgcn_s_barrier()
#define MFMA16(a, b, c) __builtin_amdgcn_mfma_f32_16x16x32_bf16(a, b, c, 0, 0, 0)
#define BC(x) __builtin_bit_cast(bf16x8, x)

// 8KB unit = 128 rows x 32 k bf16. Piece (row, s): q=row>>1,
// p = (((row&1)<<2)|s) ^ (q&7); byte = q*128 + p*16.
__device__ __forceinline__ int swz(int row, int s) {
  int q = row >> 1;
  int p = (((row & 1) << 2) | s) ^ (q & 7);
  return q * 128 + p * 16;
}

// =====================================================================
// prep: fused router (+x->bf16) | pack_gu | pack_d.  All independent.
// blocks [0,512) router ; [512, 11776) pack_gu ; [11776, 17408) pack_d.
// =====================================================================
__global__ __launch_bounds__(256) void prep_kernel(
    const float* __restrict__ x, const float* __restrict__ rw,
    ushort* __restrict__ xb, int* __restrict__ topi, float* __restrict__ topw,
    int* __restrict__ cnt, unsigned long long* __restrict__ psum,
    const float* __restrict__ wg, const float* __restrict__ wu,
    const float* __restrict__ wd, char* __restrict__ p1, char* __restrict__ p2)
{
  __shared__ char smem[16640];
  int b = blockIdx.x;

  if (b < 512) {
    // ---------------- router ----------------
    int tid = threadIdx.x, lane = tid & 63, wv = tid >> 6;
    float (*sP)[8] = (float(*)[8])smem;
    int   (*sC)[8] = (int(*)[8])(smem + 128);
    float pacc[8]; int cacc[8];
    #pragma unroll
    for (int e = 0; e < 8; ++e) { pacc[e] = 0.f; cacc[e] = 0; }

    #pragma unroll 1
    for (int it = 0; it < 4; ++it) {
      int t = b * 16 + wv * 4 + it;
      const float4* xr = (const float4*)(x + (size_t)t * DIM);
      float acc[8];
      #pragma unroll
      for (int e = 0; e < 8; ++e) acc[e] = 0.f;
      #pragma unroll 1
      for (int i = 0; i < 8; ++i) {
        int j = i * 64 + lane;
        float4 v = xr[j];
        ushort4 o; o.x = f2bf(v.x); o.y = f2bf(v.y); o.z = f2bf(v.z); o.w = f2bf(v.w);
        *(ushort4*)(xb + (size_t)t * DIM + (size_t)j * 4) = o;
        const float* rr = rw + (size_t)j * 32;
        #pragma unroll
        for (int c = 0; c < 4; ++c) {
          float xv = (&v.x)[c];
          const float4* r4 = (const float4*)(rr + c * 8);
          float4 q0 = r4[0], q1 = r4[1];
          acc[0] += xv * q0.x; acc[1] += xv * q0.y; acc[2] += xv * q0.z; acc[3] += xv * q0.w;
          acc[4] += xv * q1.x; acc[5] += xv * q1.y; acc[6] += xv * q1.z; acc[7] += xv * q1.w;
        }
      }
      #pragma unroll
      for (int off = 32; off; off >>= 1) {
        #pragma unroll
        for (int e = 0; e < 8; ++e) acc[e] += __shfl_xor(acc[e], off);
      }
      float m = acc[0];
      #pragma unroll
      for (int e = 1; e < 8; ++e) m = fmaxf(m, acc[e]);
      float p[8], s = 0.f;
      #pragma unroll
      for (int e = 0; e < 8; ++e) { p[e] = __expf(acc[e] - m); s += p[e]; }
      float inv = 1.f / s;
      int i1 = 0; float p1v = p[0];
      #pragma unroll
      for (int e = 1; e < 8; ++e) if (p[e] > p1v) { p1v = p[e]; i1 = e; }
      int i2 = -1; float p2v = -1.f;
      #pragma unroll
      for (int e = 0; e < 8; ++e) if (e != i1 && p[e] > p2v) { p2v = p[e]; i2 = e; }
      float w1 = p1v / (p1v + p2v);
      if (lane == 0) {
        topi[t] = i1 | (i2 << 8);
        topw[t] = w1;
        #pragma unroll
        for (int e = 0; e < 8; ++e) pacc[e] += p[e] * inv;
        cacc[i1]++; cacc[i2]++;
      }
    }
    if (lane == 0) {
      #pragma unroll
      for (int e = 0; e < 8; ++e) { sP[wv][e] = pacc[e]; sC[wv][e] = cacc[e]; }
    }
    __syncthreads();
    if (tid < 8) {
      float ps = sP[0][tid] + sP[1][tid] + sP[2][tid] + sP[3][tid];
      int   cs = sC[0][tid] + sC[1][tid] + sC[2][tid] + sC[3][tid];
      atomicAdd(&cnt[tid], cs);
      atomicAdd(&psum[tid], (unsigned long long)((double)ps * 1099511627776.0));
    }
  } else if (b < 11776) {
    // ---------------- pack_gu: rows 0-63 gate, 64-127 up ----------------
    int q_ = b - 512;
    int j = q_ & 63, rest = q_ >> 6;
    int tn = rest % 22, e = rest / 22;
    float (*tg)[65] = (float(*)[65])smem;
    float (*tu)[65] = (float(*)[65])(smem + 8320);
    int t = threadIdx.x;
    const float* gs = wg + ((size_t)e * DIM + j * 32) * FFN + tn * 64;
    const float* us = wu + ((size_t)e * DIM + j * 32) * FFN + tn * 64;
    #pragma unroll
    for (int k2 = 0; k2 < 2; ++k2) {
      int idx = t + k2 * 256;
      int kk = idx >> 4, fq = idx & 15;
      *(float4*)&tg[kk][fq * 4] = *(const float4*)(gs + (size_t)kk * FFN + fq * 4);
      *(float4*)&tu[kk][fq * 4] = *(const float4*)(us + (size_t)kk * FFN + fq * 4);
    }
    __syncthreads();
    char* dst = p1 + ((size_t)((e * 22 + tn) * 64 + j)) * 8192;
    #pragma unroll
    for (int k2 = 0; k2 < 2; ++k2) {
      int L = t + k2 * 256;
      int q = L >> 3, v = (L & 7) ^ (q & 7);
      int r = 2 * q + (v >> 2), s = v & 3;
      const float* col = (r < 64) ? &tg[s * 8][r] : &tu[s * 8][r - 64];
      ushort u8[8];
      #pragma unroll
      for (int i = 0; i < 8; ++i) u8[i] = f2bf(col[i * 65]);
      *(ushort4*)(dst + (size_t)L * 16) = *(ushort4*)&u8[0];
      *(ushort4*)(dst + (size_t)L * 16 + 8) = *(ushort4*)&u8[4];
    }
  } else {
    // ---------------- pack_d: rows = 128 d-cols ----------------
    int q_ = b - 11776;
    int j = q_ % 44, rest = q_ / 44;
    int tn = rest & 15, e = rest >> 4;
    float (*t2)[129] = (float(*)[129])smem;
    int t = threadIdx.x;
    const float* src = wd + ((size_t)e * FFN + j * 32) * DIM + tn * 128;
    #pragma unroll
    for (int k2 = 0; k2 < 4; ++k2) {
      int idx = t + k2 * 256;
      int kk = idx >> 5, dq = idx & 31;
      *(float4*)&t2[kk][dq * 4] = *(const float4*)(src + (size_t)kk * DIM + dq * 4);
    }
    __syncthreads();
    char* dst = p2 + ((size_t)((e * 16 + tn) * 44 + j)) * 8192;
    #pragma unroll
    for (int k2 = 0; k2 < 2; ++k2) {
      int L = t + k2 * 256;
      int q = L >> 3, v = (L & 7) ^ (q & 7);
      int r = 2 * q + (v >> 2), s = v & 3;
      ushort u8[8];
      #pragma unroll
      for (int i = 0; i < 8; ++i) u8[i] = f2bf(t2[s * 8 + i][r]);
      *(ushort4*)(dst + (size_t)L * 16) = *(ushort4*)&u8[0];
      *(ushort4*)(dst + (size_t)L * 16 + 8) = *(ushort4*)&u8[4];
    }
  }
}

// ---------------- placement (scan fused: prefix computed locally) ----------------
__global__ __launch_bounds__(256) void place_kernel(
    const int* __restrict__ topi, int* __restrict__ stats,
    const unsigned long long* __restrict__ psum,
    int* __restrict__ lpk, int2* __restrict__ tpos, float* __restrict__ aux_out)
{
  int cnt[8], pre[8];
  int acc = 0;
  #pragma unroll
  for (int e = 0; e < 8; ++e) { cnt[e] = stats[e]; pre[e] = acc; acc += cnt[e]; }

  if (blockIdx.x == 0 && threadIdx.x == 0) {
    int tb = 0;
    for (int e = 0; e < 8; ++e) {
      stats[16 + e] = pre[e];
      stats[24 + e] = tb;
      tb += (cnt[e] + 127) >> 7;
    }
    stats[32] = tb;
    double s = 0.0;
    for (int e = 0; e < 8; ++e)
      s += (double)cnt[e] * ((double)psum[e] * (1.0 / 1099511627776.0));
    aux_out[0] = (float)(4.0 * s / ((double)N_TOK * (double)N_TOK));
  }

  int t = blockIdx.x * 256 + threadIdx.x;
  if (t >= N_TOK) return;
  int pk = topi[t];
  int e1 = pk & 0xff, e2 = (pk >> 8) & 0xff;
  int p1 = pre[e1] + atomicAdd(&stats[8 + e1], 1);
  lpk[p1] = t;
  int p2 = pre[e2] + atomicAdd(&stats[8 + e2], 1);
  lpk[p2] = t;
  tpos[t] = make_int2(p1, p2);
}

// ---------------- gather bf16 tokens into chunk-image layout (x4 split) ----------------
__global__ __launch_bounds__(256) void gather_x_kernel(
    const ushort* __restrict__ xb, const int* __restrict__ lpk,
    const int* __restrict__ stats, char* __restrict__ xgp)
{
  int b = blockIdx.x;
  int tile = b >> 2;
  if (tile >= stats[32]) return;
  int e = 0;
  #pragma unroll
  for (int k = 1; k < 8; ++k) if (tile >= stats[24 + k]) e = k;
  int tloc = tile - stats[24 + e];
  int abase = stats[16 + e], Me = stats[e];
  int quad = b & 3;
  int lane = threadIdx.x & 63, wv = threadIdx.x >> 6;
  char* base = xgp + (size_t)tile * 64 * 8192;
  #pragma unroll 1
  for (int r = quad * 32 + wv; r < quad * 32 + 32; r += 4) {
    int lrow = tloc * 128 + r;
    bool valid = lrow < Me;
    const char* src = (const char*)xb + (valid ? (size_t)lpk[abase + lrow] * (DIM * 2) : 0);
    int q = r >> 1;
    #pragma unroll
    for (int it = 0; it < 4; ++it) {
      int c16 = it * 64 + lane;
      int j = c16 >> 2, s = c16 & 3;
      uint4 v;
      if (valid) v = *(const uint4*)(src + c16 * 16);
      else       v = make_uint4(0, 0, 0, 0);
      int p = (((r & 1) << 2) | s) ^ (q & 7);
      *(uint4*)(base + (size_t)j * 8192 + q * 128 + p * 16) = v;
    }
  }
}

// =====================================================================
// GEMM core: 256x128 tile (A = 2 adjacent 128-row images, B = 1 image),
// BK=32, 4 waves of 64 rows x 128 B-rows each, 3-slot LDS ring (72KB),
// prefetch depth 2, vmcnt(12)/6/0, counted lgkmcnt split (4 then 0),
// 2 blocks/CU. (Round-13 configuration — VGPR-feasible optimum; the
// 128x128/wave variant spills at 256 VGPRs.)
// XCD-locality: bid&7 -> XCD -> expert; within XCD: tm outer, tn fast.
// =====================================================================

#define GSTAGE(J, BUF) do { \
  size_t go_ = (size_t)(J) * 8192 + wv * 2048 + lane * 16; \
  int d_ = (BUF) * 24576 + wv * 2048; \
  gload16(aP0 + go_,        sm + d_); \
  gload16(aP0 + go_ + 1024, sm + d_ + 1024); \
  gload16(aP1 + go_,        sm + d_ + 8192); \
  gload16(aP1 + go_ + 1024, sm + d_ + 8192 + 1024); \
  gload16(bP + go_,         sm + d_ + 16384); \
  gload16(bP + go_ + 1024,  sm + d_ + 16384 + 1024); \
} while (0)

#define KLOOP(NCH) \
  GSTAGE(0, 0); \
  GSTAGE(1, 1); \
  { int cur = 0, st = 2; \
  _Pragma("unroll 1") \
  for (int j = 0; j < (NCH); ++j) { \
    if (j + 2 < (NCH)) { \
      GSTAGE(j + 2, st); \
      asm volatile("s_waitcnt vmcnt(12)" ::: "memory"); \
    } else if (j + 2 == (NCH)) { \
      asm volatile("s_waitcnt vmcnt(6)" ::: "memory"); \
    } else { \
      asm volatile("s_waitcnt vmcnt(0)" ::: "memory"); \
    } \
    BAR(); \
    int sb = cur * 24576; \
    int4v va[4], vb[8]; \
    _Pragma("unroll") for (int n = 0; n < 4; ++n) vb[n] = dsread(sb + adB[n]); \
    _Pragma("unroll") for (int m = 0; m < 4; ++m) va[m] = dsread(sb + adA[m]); \
    _Pragma("unroll") for (int n = 4; n < 8; ++n) vb[n] = dsread(sb + adB[n]); \
    asm volatile("s_waitcnt lgkmcnt(4)" ::: "memory"); \
    __builtin_amdgcn_sched_barrier(0); \
    __builtin_amdgcn_s_setprio(1); \
    _Pragma("unroll") for (int m = 0; m < 4; ++m) \
      _Pragma("unroll") for (int n = 0; n < 4; ++n) \
        acc[m][n] = MFMA16(BC(va[m]), BC(vb[n]), acc[m][n]); \
    __builtin_amdgcn_s_setprio(0); \
    asm volatile("s_waitcnt lgkmcnt(0)" ::: "memory"); \
    __builtin_amdgcn_sched_barrier(0); \
    __builtin_amdgcn_s_setprio(1); \
    _Pragma("unroll") for (int m = 0; m < 4; ++m) \
      _Pragma("unroll") for (int n = 4; n < 8; ++n) \
        acc[m][n] = MFMA16(BC(va[m]), BC(vb[n]), acc[m][n]); \
    __builtin_amdgcn_s_setprio(0); \
    BAR(); \
    cur = (cur == 2) ? 0 : cur + 1; \
    st  = (st  == 2) ? 0 : st  + 1; \
  } }

// GEMM1: A = 256 tokens (2 images), B = {gate,up} image (rows 0-63 g, 64-127 u
// per 64 f-cols). Wave owns 64 tokens x all 128 B-rows -> SiLU in-register.
__global__ __launch_bounds__(256, 2) void gemm_gu_kernel(
    const char* __restrict__ xgp, const char* __restrict__ p1,
    const int* __restrict__ stats, char* __restrict__ hp)
{
  int bid = blockIdx.x;
  int e = bid & 7;
  int Ll = bid >> 3;
  int tm = Ll / 22, tn = Ll % 22;
  int Me = stats[e];
  if (tm * 256 >= Me) return;
  int tb = stats[24 + e];

  __shared__ char sm[73728];
  int tid = threadIdx.x, lane = tid & 63, wv = tid >> 6;
  const char* aP0 = xgp + (size_t)(tb + tm * 2) * 64 * 8192;
  const char* aP1 = aP0 + 64 * 8192;
  const char* bP = p1 + (size_t)((e * 22 + tn) * 64) * 8192;

  int s = lane >> 4;
  int adA[4], adB[8];
  #pragma unroll
  for (int m = 0; m < 4; ++m) {
    int row = wv * 64 + m * 16 + (lane & 15);
    adA[m] = (row >> 7) * 8192 + swz(row & 127, s);
  }
  #pragma unroll
  for (int n = 0; n < 8; ++n) adB[n] = 16384 + swz(n * 16 + (lane & 15), s);

  f32x4 acc[4][8];
  #pragma unroll
  for (int m = 0; m < 4; ++m)
    #pragma unroll
    for (int n = 0; n < 8; ++n) acc[m][n] = (f32x4){0, 0, 0, 0};

  KLOOP(64);

  // epilogue: gate = acc[m][n], up = acc[m][n+4] (same f-col) -> in-register SiLU.
  int r0 = (lane >> 4) * 4, cl = lane & 15;
  #pragma unroll
  for (int m = 0; m < 4; ++m) {
    #pragma unroll
    for (int r = 0; r < 4; ++r) {
      int row = wv * 64 + m * 16 + r0 + r;
      if (tm * 256 + row < Me) {
        char* hb = hp + (size_t)(tb + tm * 2 + (row >> 7)) * 44 * 8192;
        int lr = row & 127;
        int q = lr >> 1;
        #pragma unroll
        for (int n = 0; n < 4; ++n) {
          float g = acc[m][n][r];
          float u = acc[m][n + 4][r];
          float hv = g * u / (1.f + __expf(-g));
          int f = tn * 64 + n * 16 + cl;
          int j2 = f >> 5, s2 = (f >> 3) & 3, i2 = f & 7;
          int p = (((lr & 1) << 2) | s2) ^ (q & 7);
          *(ushort*)(hb + (size_t)j2 * 8192 + q * 128 + p * 16 + i2 * 2) = f2bf(hv);
        }
      }
    }
  }
}

// GEMM2: A = h (2 images), B = down image (128 d-cols); dense bf16 store to eo.
__global__ __launch_bounds__(256, 2) void gemm_down_kernel(
    const char* __restrict__ hp, const char* __restrict__ p2,
    const int* __restrict__ stats, ushort* __restrict__ eo)
{
  int bid = blockIdx.x;
  int e = bid & 7;
  int Ll = bid >> 3;
  int tm = Ll >> 4, tn = Ll & 15;
  int Me = stats[e];
  if (tm * 256 >= Me) return;
  int tb = stats[24 + e], abase = stats[16 + e];

  __shared__ char sm[73728];
  int tid = threadIdx.x, lane = tid & 63, wv = tid >> 6;
  const char* aP0 = hp + (size_t)(tb + tm * 2) * 44 * 8192;
  const char* aP1 = aP0 + 44 * 8192;
  const char* bP = p2 + (size_t)((e * 16 + tn) * 44) * 8192;

  int s = lane >> 4;
  int adA[4], adB[8];
  #pragma unroll
  for (int m = 0; m < 4; ++m) {
    int row = wv * 64 + m * 16 + (lane & 15);
    adA[m] = (row >> 7) * 8192 + swz(row & 127, s);
  }
  #pragma unroll
  for (int n = 0; n < 8; ++n) adB[n] = 16384 + swz(n * 16 + (lane & 15), s);

  f32x4 acc[4][8];
  #pragma unroll
  for (int m = 0; m < 4; ++m)
    #pragma unroll
    for (int n = 0; n < 8; ++n) acc[m][n] = (f32x4){0, 0, 0, 0};

  KLOOP(44);

  int c0 = lane & 15, r0 = (lane >> 4) * 4;
  #pragma unroll
  for (int m = 0; m < 4; ++m) {
    #pragma unroll
    for (int r = 0; r < 4; ++r) {
      int lrow = tm * 256 + wv * 64 + m * 16 + r0 + r;
      if (lrow < Me) {
        ushort* dst = eo + (size_t)(abase + lrow) * DIM + tn * 128 + c0;
        #pragma unroll
        for (int n = 0; n < 8; ++n) dst[n * 16] = f2bf(acc[m][n][r]);
      }
    }
  }
}

// ---------------- combine: out[t] = w1*eo[p1] + w2*eo[p2] (bf16 partials) ----------------
__global__ __launch_bounds__(256) void combine_kernel(
    const ushort* __restrict__ eo, const int2* __restrict__ tpos,
    const float* __restrict__ topw, float* __restrict__ out)
{
  int t = blockIdx.x;
  int2 tp = tpos[t];
  float w1 = topw[t], w2 = 1.f - w1;
  const uint4* r1 = (const uint4*)(eo + (size_t)tp.x * DIM);
  const uint4* r2 = (const uint4*)(eo + (size_t)tp.y * DIM);
  float4* o = (float4*)(out + (size_t)t * DIM);
  int i = threadIdx.x;
  uint4 a = r1[i], b = r2[i];
  float4 c0, c1;
  c0.x = w1 * blo(a.x) + w2 * blo(b.x);  c0.y = w1 * bhi(a.x) + w2 * bhi(b.x);
  c0.z = w1 * blo(a.y) + w2 * blo(b.y);  c0.w = w1 * bhi(a.y) + w2 * bhi(b.y);
  c1.x = w1 * blo(a.z) + w2 * blo(b.z);  c1.y = w1 * bhi(a.z) + w2 * bhi(b.z);
  c1.z = w1 * blo(a.w) + w2 * blo(b.w);  c1.w = w1 * bhi(a.w) + w2 * bhi(b.w);
  o[i * 2] = c0;
  o[i * 2 + 1] = c1;
}

extern "C" void kernel_launch(void* const* d_in, const int* in_sizes, int n_in,
                              void* d_out, int out_size, void* d_ws, size_t ws_size,
                              hipStream_t stream)
{
  const float* x  = (const float*)d_in[0];
  const float* rw = (const float*)d_in[1];
  const float* wg = (const float*)d_in[2];
  const float* wu = (const float*)d_in[3];
  const float* wd = (const float*)d_in[4];
  float* out = (float*)d_out;

  char* ws = (char*)d_ws;
  ushort* xb   = (ushort*)(ws + XB_OFF);
  char*   hp   = ws + HP_OFF;
  char*   xgp  = ws + XGP_OFF;
  ushort* eo   = (ushort*)(ws + EO_OFF);
  char*   p1   = ws + P1_OFF;
  char*   p2   = ws + P2_OFF;
  int*    lpk  = (int*)(ws + LPK_OFF);
  int*    topi = (int*)(ws + TI_OFF);
  float*  topw = (float*)(ws + TW_OFF);
  int2*   tpos = (int2*)(ws + TP_OFF);
  int*    stats = (int*)(ws + ST_OFF);
  unsigned long long* psum = (unsigned long long*)(ws + ST_OFF + 192);

  hipMemsetAsync(ws + ST_OFF, 0, 256, stream);

  prep_kernel<<<17408, 256, 0, stream>>>(x, rw, xb, topi, topw, stats, psum,
                                         wg, wu, wd, p1, p2);
  place_kernel<<<32, 256, 0, stream>>>(topi, stats, psum, lpk, tpos,
                                       out + (size_t)out_size - 1);

  gather_x_kernel<<<544, 256, 0, stream>>>(xb, lpk, stats, xgp);

  gemm_gu_kernel<<<2816, 256, 0, stream>>>(xgp, p1, stats, hp);
  gemm_down_kernel<<<2048, 256, 0, stream>>>(hp, p2, stats, eo);

  combine_kernel<<<8192, 256, 0, stream>>>(eo, tpos, topw, out);
}